// Round 1
// baseline (361.003 us; speedup 1.0000x reference)
//
#include <hip/hip_runtime.h>
#include <math.h>

#define B_ 4096
#define F_ 24
#define D_ 16
// emb row = 2*D_ = 32 floats = 128 bytes

// 16 lanes cooperate on one batch row. Lane l reads float2 at columns [2l, 2l+1]
// of each gathered emb row -> the 16-lane segment covers the 128B row contiguously
// (one coalesced access per field). Lanes 0-7 own the order-2 half (cols 0..15),
// lanes 8-15 the order-3 half (cols 16..31). All lanes accumulate power sums
// p1,p2,p3 branchlessly; the final formula is selected by lane.
__global__ __launch_bounds__(256) void fm_ho_kernel(
    const int*   __restrict__ x,
    const int*   __restrict__ offsets,
    const float* __restrict__ w_linear,
    const float* __restrict__ bias,
    const float* __restrict__ emb,
    float*       __restrict__ out)
{
    const int tid   = threadIdx.x;
    const int lane  = tid & 15;        // position within 16-lane segment
    const int group = tid >> 4;        // row-group within block
    const int b     = blockIdx.x * (blockDim.x >> 4) + group;

    const int* xrow = x + b * F_;

    float p1x = 0.f, p2x = 0.f, p3x = 0.f;
    float p1y = 0.f, p2y = 0.f, p3y = 0.f;
    float slin = 0.f;

    #pragma unroll
    for (int f = 0; f < F_; ++f) {
        const int    idx = xrow[f] + offsets[f];
        const size_t row = (size_t)idx * (2 * D_);
        const float2 v   = *(const float2*)(emb + row + 2 * lane);

        // power sums for this lane's two columns
        p1x += v.x;              p1y += v.y;
        p2x += v.x * v.x;        p2y += v.y * v.y;
        p3x += v.x * v.x * v.x;  p3y += v.y * v.y * v.y;

        // linear term: distribute the 24 w_linear gathers over the 16 lanes
        if (lane == (f & 15)) slin += w_linear[idx];
    }

    float part = slin;
    if (lane < 8) {
        // e2 = 0.5*(p1^2 - p2), summed over this lane's 2 columns
        part += 0.5f * ((p1x * p1x - p2x) + (p1y * p1y - p2y));
    } else {
        // e3 = (p1^3 - 3 p1 p2 + 2 p3)/6
        part += (1.0f / 6.0f) *
                ((p1x * p1x * p1x - 3.f * p1x * p2x + 2.f * p3x) +
                 (p1y * p1y * p1y - 3.f * p1y * p2y + 2.f * p3y));
    }

    // reduce across the 16-lane segment (stays inside the wave, width=16)
    #pragma unroll
    for (int off = 8; off > 0; off >>= 1)
        part += __shfl_xor(part, off, 16);

    if (lane == 0) {
        const float y = part + bias[0];
        out[b] = 1.0f / (1.0f + __expf(-y));
    }
}

extern "C" void kernel_launch(void* const* d_in, const int* in_sizes, int n_in,
                              void* d_out, int out_size, void* d_ws, size_t ws_size,
                              hipStream_t stream) {
    const int*   x       = (const int*)  d_in[0];
    const int*   offsets = (const int*)  d_in[1];
    const float* w       = (const float*)d_in[2];
    const float* bias    = (const float*)d_in[3];
    const float* emb     = (const float*)d_in[4];
    float*       out     = (float*)      d_out;

    const int rows_per_block = 256 / 16;              // 16
    const int grid           = B_ / rows_per_block;   // 256 blocks
    fm_ho_kernel<<<grid, 256, 0, stream>>>(x, offsets, w, bias, emb, out);
}

// Round 2
// 349.289 us; speedup vs baseline: 1.0335x; 1.0335x over previous
//
#include <hip/hip_runtime.h>
#include <math.h>

#define B_ 4096
#define F_ 24
#define C_ 32      // floats per emb row (128 B)
#define HALF_F 12  // fields per half-wave

// One 64-lane wave per batch row.
//   lane = h*32 + c :  c = column (0..31) of the 128B emb row,
//                      h = field half (h=0 -> fields 0..11, h=1 -> fields 12..23)
// Each half's 32 lanes read one contiguous 128B row segment per field ->
// a 64-lane load instruction covers 2 random 128B rows, fully coalesced.
// Power sums p1,p2,p3 per column; halves combined with shfl_xor(32);
// e2 = (p1^2-p2)/2 on cols 0..15, e3 = (p1^3-3p1p2+2p3)/6 on cols 16..31
// (Newton's identities; validated in R1).
__global__ __launch_bounds__(256) void fm_ho_kernel(
    const int*   __restrict__ x,
    const int*   __restrict__ offsets,
    const float* __restrict__ w_linear,
    const float* __restrict__ bias,
    const float* __restrict__ emb,
    float*       __restrict__ out)
{
    const int tid  = threadIdx.x;
    const int lane = tid & 63;
    const int wave = tid >> 6;
    const int b    = blockIdx.x * 4 + wave;

    const int c = lane & 31;   // column within emb row
    const int h = lane >> 5;   // which half of the fields

    // Lanes 0..23 each own one field: compute its gather index and issue the
    // w_linear gather immediately (overlaps with everything below).
    const int lf   = (lane < F_) ? lane : 0;
    const int idxl = x[b * F_ + lf] + offsets[lf];
    float wl = 0.f;
    if (lane < F_) wl = w_linear[idxl];

    // Broadcast my half's 12 field indices, then issue all 12 emb gathers
    // back-to-back (address array first -> loads batch before any waitcnt).
    int rows[HALF_F];
    #pragma unroll
    for (int j = 0; j < HALF_F; ++j)
        rows[j] = __shfl(idxl, h * HALF_F + j, 64);

    float v[HALF_F];
    #pragma unroll
    for (int j = 0; j < HALF_F; ++j)
        v[j] = emb[(size_t)rows[j] * C_ + c];

    float p1 = 0.f, p2 = 0.f, p3 = 0.f;
    #pragma unroll
    for (int j = 0; j < HALF_F; ++j) {
        const float t = v[j];
        p1 += t;
        p2 += t * t;
        p3 += t * t * t;
    }

    // combine field-halves (lane ^ 32): full power sums per column
    p1 += __shfl_xor(p1, 32, 64);
    p2 += __shfl_xor(p2, 32, 64);
    p3 += __shfl_xor(p3, 32, 64);

    float term;
    if (c < 16)
        term = 0.5f * (p1 * p1 - p2);
    else
        term = (1.0f / 6.0f) * (p1 * p1 * p1 - 3.f * p1 * p2 + 2.f * p3);

    // contrib: linear part lives on lanes 0..23; column terms only on h==0
    // so the 64-lane reduction counts each exactly once.
    float contrib = wl + ((h == 0) ? term : 0.f);
    #pragma unroll
    for (int off = 32; off > 0; off >>= 1)
        contrib += __shfl_xor(contrib, off, 64);

    if (lane == 0)
        out[b] = 1.0f / (1.0f + __expf(-(contrib + bias[0])));
}

extern "C" void kernel_launch(void* const* d_in, const int* in_sizes, int n_in,
                              void* d_out, int out_size, void* d_ws, size_t ws_size,
                              hipStream_t stream) {
    const int*   x       = (const int*)  d_in[0];
    const int*   offsets = (const int*)  d_in[1];
    const float* w       = (const float*)d_in[2];
    const float* bias    = (const float*)d_in[3];
    const float* emb     = (const float*)d_in[4];
    float*       out     = (float*)      d_out;

    // 1 wave per row, 4 waves per block -> 1024 blocks, 4096 waves (16/CU)
    fm_ho_kernel<<<B_ / 4, 256, 0, stream>>>(x, offsets, w, bias, emb, out);
}